// Round 4
// baseline (915.689 us; speedup 1.0000x reference)
//
#include <hip/hip_runtime.h>
#include <cstdint>
#include <cstddef>

// Dims (fixed by the problem)
#define BB 8
#define CC 128
#define C3 384
#define HH 64
#define H2 32
#define NPIX 1024   // 32*32
#define N4 4096     // 64*64
#define NHD 8
#define HD 16

// ---------------- K1: Haar DWT ----------------
__global__ __launch_bounds__(256) void k_dwt(const float* __restrict__ x,
                                             float* __restrict__ ll,
                                             float* __restrict__ high) {
  int idx = blockIdx.x * 256 + threadIdx.x;   // B*C*32*32 = 1,048,576
  int w = idx & 31, h = (idx >> 5) & 31, c = (idx >> 10) & 127, b = idx >> 17;
  const float* xp = x + ((size_t)(b * CC + c) * HH + 2 * h) * HH + 2 * w;
  float x1 = xp[0];
  float x2 = xp[HH];
  float x3 = xp[1];
  float x4 = xp[HH + 1];
  int n = h * H2 + w;
  ll[(size_t)(b * CC + c) * NPIX + n]              = 0.5f * ( x1 + x2 + x3 + x4);
  high[((size_t)b * C3 + c) * NPIX + n]            = 0.5f * (-x1 - x2 + x3 + x4);
  high[((size_t)b * C3 + CC + c) * NPIX + n]       = 0.5f * (-x1 + x2 - x3 + x4);
  high[((size_t)b * C3 + 2 * CC + c) * NPIX + n]   = 0.5f * ( x1 - x2 - x3 + x4);
}

// ---------------- conv1x1: pure-register GEMV per pixel ----------------
template <int CIN, int P>
__global__ __launch_bounds__(256) void k_conv1x1(const float* __restrict__ in,
                                                 const float* __restrict__ w,
                                                 float* __restrict__ out,
                                                 int Cout, int Npix) {
  int tid = threadIdx.x;
  int n0 = (blockIdx.x * 256 + tid) * P;
  int o0 = blockIdx.y * 16;
  int b = blockIdx.z;
  const float* inb = in + (size_t)b * CIN * Npix + n0;
  const float* wb = w + (size_t)o0 * CIN;
  float acc[16][P];
#pragma unroll
  for (int o = 0; o < 16; ++o)
#pragma unroll
    for (int p = 0; p < P; ++p) acc[o][p] = 0.f;

  for (int c0 = 0; c0 < CIN; c0 += 8) {
#pragma unroll
    for (int c = 0; c < 8; ++c) {
      float vv[P];
      const float* ip = inb + (size_t)(c0 + c) * Npix;
      if constexpr (P == 4) {
        float4 t = *(const float4*)ip;
        vv[0] = t.x; vv[1] = t.y; vv[2] = t.z; vv[3] = t.w;
      } else if constexpr (P == 2) {
        float2 t = *(const float2*)ip;
        vv[0] = t.x; vv[1] = t.y;
      } else {
        vv[0] = ip[0];
      }
#pragma unroll
      for (int o = 0; o < 16; ++o) {
        float wc = wb[(size_t)o * CIN + c0 + c];   // uniform -> s_load
#pragma unroll
        for (int p = 0; p < P; ++p) acc[o][p] = fmaf(wc, vv[p], acc[o][p]);
      }
    }
  }
  size_t ob = ((size_t)b * Cout + o0) * Npix + n0;
#pragma unroll
  for (int o = 0; o < 16; ++o) {
    float* op = out + ob + (size_t)o * Npix;
    if constexpr (P == 4) {
      *(float4*)op = make_float4(acc[o][0], acc[o][1], acc[o][2], acc[o][3]);
    } else if constexpr (P == 2) {
      *(float2*)op = make_float2(acc[o][0], acc[o][1]);
    } else {
      op[0] = acc[o][0];
    }
  }
}

// ---------------- K2b: split qkv + l2norm q,k ----------------
__global__ __launch_bounds__(256) void k_qkvnorm(const float* __restrict__ qkv,
                                                 float* __restrict__ qn,
                                                 float* __restrict__ kn,
                                                 float* __restrict__ vout) {
  int idx = blockIdx.x * 256 + threadIdx.x;  // 65536 = B*NH*NPIX
  int n = idx & 1023, h = (idx >> 10) & 7, b = idx >> 13;
  const float* base = qkv + ((size_t)b * C3 + h * HD) * NPIX + n;
  float q[HD], k[HD], vv[HD];
  float sq = 0.f, sk = 0.f;
#pragma unroll
  for (int d = 0; d < HD; ++d) {
    q[d] = base[(size_t)d * NPIX];
    k[d] = base[(size_t)(CC + d) * NPIX];
    vv[d] = base[(size_t)(2 * CC + d) * NPIX];
    sq += q[d] * q[d];
    sk += k[d] * k[d];
  }
  float rq = 1.f / fmaxf(sqrtf(sq), 1e-12f);
  float rk = 1.f / fmaxf(sqrtf(sk), 1e-12f);
  float4* qo = (float4*)(qn + (size_t)idx * HD);
  float4* ko = (float4*)(kn + (size_t)idx * HD);
  float4* vo = (float4*)(vout + (size_t)idx * HD);
#pragma unroll
  for (int d4 = 0; d4 < 4; ++d4) {
    qo[d4] = make_float4(q[4*d4]*rq, q[4*d4+1]*rq, q[4*d4+2]*rq, q[4*d4+3]*rq);
    ko[d4] = make_float4(k[4*d4]*rk, k[4*d4+1]*rk, k[4*d4+2]*rk, k[4*d4+3]*rk);
    vo[d4] = make_float4(vv[4*d4], vv[4*d4+1], vv[4*d4+2], vv[4*d4+3]);
  }
}

// ---------------- K3: sparse top-k attention ----------------
// 4 q-rows per wave; lane L covers keys {i*64 + L}. K/V loaded once per
// wave, reused for 4 q-rows. q staged via LDS -> VGPRs (broadcast reads).
// Scores bounded: |s| = |q_hat . k_hat|*0.25 <= 0.25 -> no clip, no
// max-subtract, fixed bisection bounds. Bisection counts via ballot+popcll
// (SALU-side accumulate). p overwrites the score array in place (no extra
// registers, no format conversion). __launch_bounds__(256,3) pins the
// allocator to <=~170 VGPR: no spill (round-3 lesson) and 3 waves/SIMD.
__global__ __launch_bounds__(256, 3) void k_attn(const float* __restrict__ qn,
                                                 const float* __restrict__ kn,
                                                 const float* __restrict__ v,
                                                 float* __restrict__ attn_out) {
  __shared__ float q_lds[256];
  int tid = threadIdx.x;
  int lane = tid & 63;
  int wave = tid >> 6;
  int blk = blockIdx.x;            // 4096 blocks; 64 blocks per (b,h)
  int row0 = blk * 16;
  int bh = blk >> 6;
  // stage the block's 16 q-vectors (256 consecutive floats, coalesced)
  q_lds[tid] = qn[(size_t)row0 * HD + tid];
  __syncthreads();
  // this wave's 4 q rows -> VGPRs (wave-uniform LDS reads = broadcast)
  float qs[4][16];
  const float4* qw = (const float4*)&q_lds[wave * 64];
#pragma unroll
  for (int q = 0; q < 4; ++q)
#pragma unroll
    for (int d4 = 0; d4 < 4; ++d4) {
      float4 t = qw[q * 4 + d4];
      qs[q][4*d4] = t.x; qs[q][4*d4+1] = t.y; qs[q][4*d4+2] = t.z; qs[q][4*d4+3] = t.w;
    }

  const float* kb = kn + (size_t)bh * NPIX * HD;
  const float* vb = v  + (size_t)bh * NPIX * HD;

  // ---- phase 1: scores ----
  float s[4][16];
#pragma unroll 4
  for (int i = 0; i < 16; ++i) {
    const float* krow = kb + (size_t)(i * 64 + lane) * HD;
    float kr[16];
#pragma unroll
    for (int d4 = 0; d4 < 4; ++d4) {
      float4 t = ((const float4*)krow)[d4];
      kr[4*d4] = t.x; kr[4*d4+1] = t.y; kr[4*d4+2] = t.z; kr[4*d4+3] = t.w;
    }
#pragma unroll
    for (int q = 0; q < 4; ++q) {
      float acc = 0.f;
#pragma unroll
      for (int d = 0; d < 16; ++d) acc = fmaf(qs[q][d], kr[d], acc);
      s[q][i] = acc * 0.25f;
    }
  }

  // ---- bisect for 512th-largest: ballot + popc (SALU adds) ----
  float lo[4], hi[4];
#pragma unroll
  for (int q = 0; q < 4; ++q) { lo[q] = -0.26f; hi[q] = 0.26f; }
  for (int it = 0; it < 14; ++it) {
#pragma unroll
    for (int q = 0; q < 4; ++q) {
      float mid = 0.5f * (lo[q] + hi[q]);
      int c = 0;
#pragma unroll
      for (int k = 0; k < 16; ++k)
        c += __popcll(__ballot(s[q][k] >= mid));
      if (c >= 512) lo[q] = mid; else hi[q] = mid;
    }
  }

  // ---- masked softmax in place (s -> unnormalized p) ----
  float inv[4];
#pragma unroll
  for (int q = 0; q < 4; ++q) {
    float sum = 0.f;
#pragma unroll
    for (int k = 0; k < 16; ++k) {
      float p = (s[q][k] >= lo[q]) ? __expf(s[q][k]) : 0.f;   // s in [-.25,.25]
      s[q][k] = p;
      sum += p;
    }
#pragma unroll
    for (int off = 32; off > 0; off >>= 1) sum += __shfl_xor(sum, off);
    inv[q] = 1.f / sum;
  }

  // ---- phase 2: AV ----
  float ov[4][16];
#pragma unroll
  for (int q = 0; q < 4; ++q)
#pragma unroll
    for (int d = 0; d < 16; ++d) ov[q][d] = 0.f;
#pragma unroll 4
  for (int i = 0; i < 16; ++i) {
    const float* vrow = vb + (size_t)(i * 64 + lane) * HD;
    float vr[16];
#pragma unroll
    for (int d4 = 0; d4 < 4; ++d4) {
      float4 t = ((const float4*)vrow)[d4];
      vr[4*d4] = t.x; vr[4*d4+1] = t.y; vr[4*d4+2] = t.z; vr[4*d4+3] = t.w;
    }
#pragma unroll
    for (int q = 0; q < 4; ++q) {
      float pj = s[q][i];
#pragma unroll
      for (int d = 0; d < 16; ++d) ov[q][d] = fmaf(pj, vr[d], ov[q][d]);
    }
  }

  // ---- fold-transpose reduce: lane (L&15) ends with total for dim L&15 ----
  int b = bh >> 3, h = bh & 7;
#pragma unroll
  for (int q = 0; q < 4; ++q) {
    float A[16], R[16];
#pragma unroll
    for (int i = 0; i < 16; ++i) A[i] = ov[q][i];
#pragma unroll
    for (int i = 0; i < 16; ++i) R[i] = __shfl_xor(A[i], 1);
    bool m0 = (lane & 1) != 0;
    float B8[8];
#pragma unroll
    for (int p = 0; p < 8; ++p)
      B8[p] = m0 ? (A[2 * p + 1] + R[2 * p + 1]) : (A[2 * p] + R[2 * p]);
    float R8[8];
#pragma unroll
    for (int p = 0; p < 8; ++p) R8[p] = __shfl_xor(B8[p], 2);
    bool m1 = (lane & 2) != 0;
    float B4[4];
#pragma unroll
    for (int p = 0; p < 4; ++p)
      B4[p] = m1 ? (B8[2 * p + 1] + R8[2 * p + 1]) : (B8[2 * p] + R8[2 * p]);
    float R4[4];
#pragma unroll
    for (int p = 0; p < 4; ++p) R4[p] = __shfl_xor(B4[p], 4);
    bool m2 = (lane & 4) != 0;
    float B2[2];
#pragma unroll
    for (int p = 0; p < 2; ++p)
      B2[p] = m2 ? (B4[2 * p + 1] + R4[2 * p + 1]) : (B4[2 * p] + R4[2 * p]);
    float R2[2];
    R2[0] = __shfl_xor(B2[0], 8);
    R2[1] = __shfl_xor(B2[1], 8);
    bool m3 = (lane & 8) != 0;
    float w1 = m3 ? (B2[1] + R2[1]) : (B2[0] + R2[0]);
    w1 += __shfl_xor(w1, 16);
    w1 += __shfl_xor(w1, 32);
    if (lane < 16) {
      int r = row0 + wave * 4 + q;
      int n = r & 1023;
      attn_out[((size_t)(b * CC + h * HD + lane) * NPIX) + n] = w1 * inv[q];
    }
  }
}

// ---------------- K5a: depthwise 3x3 SAME conv ----------------
__global__ __launch_bounds__(256) void k_dwconv(const float* __restrict__ in,
                                                const float* __restrict__ w,
                                                float* __restrict__ out) {
  int n = blockIdx.x * 256 + threadIdx.x;
  int c = blockIdx.y, b = blockIdx.z;
  int i = n >> 5, j = n & 31;
  const float* inb = in + ((size_t)b * C3 + c) * NPIX;
  const float* wc = w + c * 9;
  float acc = 0.f;
#pragma unroll
  for (int di = -1; di <= 1; ++di) {
    int ii = i + di;
    if (ii < 0 || ii > 31) continue;
#pragma unroll
    for (int dj = -1; dj <= 1; ++dj) {
      int jj = j + dj;
      if (jj < 0 || jj > 31) continue;
      acc += inb[ii * 32 + jj] * wc[(di + 1) * 3 + (dj + 1)];
    }
  }
  out[((size_t)b * C3 + c) * NPIX + n] = acc;
}

// ---------------- GroupNorm (32 groups) + fused epilogue, float4, 512 thr ----
template <int ACT, bool HAS_RES>
__global__ __launch_bounds__(512) void k_gn(const float* __restrict__ x,
                                            const float* __restrict__ res,
                                            float* __restrict__ out,
                                            const float* __restrict__ gamma,
                                            const float* __restrict__ beta,
                                            const float* __restrict__ alpha_ptr,
                                            float alpha_const,
                                            int chPerGroup, int Npix, int nshift) {
  int g = blockIdx.x & 31, b = blockIdx.x >> 5;
  int Cout = 32 * chPerGroup;
  int elems = chPerGroup * Npix;
  int nv = elems >> 2;
  size_t base = ((size_t)b * Cout + g * chPerGroup) * Npix;
  const float4* xv = (const float4*)(x + base);
  int tid = threadIdx.x;
  float s = 0.f, s2 = 0.f;
  for (int i = tid; i < nv; i += 512) {
    float4 v = xv[i];
    s += v.x + v.y + v.z + v.w;
    s2 += v.x * v.x + v.y * v.y + v.z * v.z + v.w * v.w;
  }
  __shared__ float ls[512], ls2[512];
  ls[tid] = s; ls2[tid] = s2;
  __syncthreads();
  for (int st = 256; st > 0; st >>= 1) {
    if (tid < st) { ls[tid] += ls[tid + st]; ls2[tid] += ls2[tid + st]; }
    __syncthreads();
  }
  float inv_n = 1.f / (float)elems;
  float mean = ls[0] * inv_n;
  float var = ls2[0] * inv_n - mean * mean;
  float rstd = rsqrtf(var + 1e-6f);
  float a = alpha_ptr ? alpha_ptr[0] : alpha_const;
  const float4* rv = (const float4*)(res + base);
  float4* ov = (float4*)(out + base);
  int cshift = nshift - 2;
  for (int i = tid; i < nv; i += 512) {
    float4 v = xv[i];
    int cc = g * chPerGroup + (i >> cshift);
    float gm = gamma[cc], bt = beta[cc];
    float r[4] = {v.x, v.y, v.z, v.w};
#pragma unroll
    for (int p = 0; p < 4; ++p) {
      float gnv = (r[p] - mean) * rstd * gm + bt;
      if (ACT == 1)      r[p] = gnv / (1.f + __expf(-gnv));
      else if (ACT == 2) r[p] = 0.5f * gnv * (1.f + erff(gnv * 0.70710678118654752f));
      else               r[p] = gnv;
    }
    float4 o;
    if (HAS_RES) {
      float4 rr = rv[i];
      o = make_float4(rr.x + a * r[0], rr.y + a * r[1], rr.z + a * r[2], rr.w + a * r[3]);
    } else {
      o = make_float4(r[0], r[1], r[2], r[3]);
    }
    ov[i] = o;
  }
}

// ---------------- K6: IWT + residual ----------------
__global__ __launch_bounds__(256) void k_iwt(const float* __restrict__ x,
                                             const float* __restrict__ s1,
                                             const float* __restrict__ hout,
                                             float* __restrict__ out) {
  int idx = blockIdx.x * 256 + threadIdx.x;  // B*C*32*32
  int w = idx & 31, h = (idx >> 5) & 31, c = (idx >> 10) & 127, b = idx >> 17;
  int n = h * 32 + w;
  float ll = s1[(size_t)(b * CC + c) * NPIX + n];
  float lh = hout[((size_t)b * C3 + c) * NPIX + n];
  float hl = hout[((size_t)b * C3 + CC + c) * NPIX + n];
  float hh = hout[((size_t)b * C3 + 2 * CC + c) * NPIX + n];
  float va = ll - lh - hl + hh;
  float vb = ll - lh + hl - hh;
  float vc = ll + lh - hl - hh;
  float vd = ll + lh + hl + hh;
  size_t xb = ((size_t)(b * CC + c) * HH + 2 * h) * HH + 2 * w;
  out[xb]          = x[xb]          + 0.1f * va;
  out[xb + 1]      = x[xb + 1]      + 0.1f * vc;
  out[xb + HH]     = x[xb + HH]     + 0.1f * vb;
  out[xb + HH + 1] = x[xb + HH + 1] + 0.1f * vd;
}

extern "C" void kernel_launch(void* const* d_in, const int* in_sizes, int n_in,
                              void* d_out, int out_size, void* d_ws, size_t ws_size,
                              hipStream_t stream) {
  const float* x         = (const float*)d_in[0];
  const float* qkv_w     = (const float*)d_in[1];
  const float* proj_w    = (const float*)d_in[2];
  const float* attn_gn_g = (const float*)d_in[3];
  const float* attn_gn_b = (const float*)d_in[4];
  const float* he_dw_w   = (const float*)d_in[5];
  const float* he_gn1_g  = (const float*)d_in[6];
  const float* he_gn1_b  = (const float*)d_in[7];
  const float* he_pw_w   = (const float*)d_in[8];
  const float* he_gn2_g  = (const float*)d_in[9];
  const float* he_gn2_b  = (const float*)d_in[10];
  const float* alpha     = (const float*)d_in[11];
  const float* ffn_w1    = (const float*)d_in[12];
  const float* ffn_gn1_g = (const float*)d_in[13];
  const float* ffn_gn1_b = (const float*)d_in[14];
  const float* ffn_w2    = (const float*)d_in[15];
  const float* ffn_gn2_g = (const float*)d_in[16];
  const float* ffn_gn2_b = (const float*)d_in[17];
  float* out = (float*)d_out;

  float* ws = (float*)d_ws;
  float* ll   = ws;              // 1,048,576
  float* high = ws + 1048576;    // 3,145,728
  float* qkv  = ws + 4194304;    // 3,145,728 ; reused as y1
  float* qnkv = ws + 7340032;    // 3,145,728 ; qn|kn|v ; reused as pw/h_out
  float* atto = ws + 10485760;   // 1,048,576
  float* proj = ws + 11534336;   // 1,048,576
  float* f1   = ws + 12582912;   // 8,388,608
  float* f3   = ws + 20971520;   // 4,194,304
  float* qn = qnkv;
  float* kn = qnkv + 1048576;
  float* vv = qnkv + 2097152;
  float* y1 = qkv;
  float* pw = qnkv;

  // 1) DWT
  k_dwt<<<4096, 256, 0, stream>>>(x, ll, high);
  // 2) qkv = conv1x1(ll, qkv_w); split + l2norm
  k_conv1x1<128, 2><<<dim3(2, 24, 8), 256, 0, stream>>>(ll, qkv_w, qkv, 384, 1024);
  k_qkvnorm<<<256, 256, 0, stream>>>(qkv, qn, kn, vv);
  // 3) sparse attention (4 q-rows per wave)
  k_attn<<<4096, 256, 0, stream>>>(qn, kn, vv, atto);
  // 4) proj + groupnorm, s1 = ll + gn(proj)
  k_conv1x1<128, 1><<<dim3(4, 8, 8), 256, 0, stream>>>(atto, proj_w, proj, 128, 1024);
  k_gn<0, true><<<256, 512, 0, stream>>>(proj, ll, proj, attn_gn_g, attn_gn_b,
                                         nullptr, 1.0f, 4, 1024, 10);
  // 5) high enhance
  k_dwconv<<<dim3(4, 384, 8), 256, 0, stream>>>(high, he_dw_w, y1);
  k_gn<1, false><<<256, 512, 0, stream>>>(y1, nullptr, y1, he_gn1_g, he_gn1_b,
                                          nullptr, 0.f, 12, 1024, 10);
  k_conv1x1<384, 2><<<dim3(2, 24, 8), 256, 0, stream>>>(y1, he_pw_w, pw, 384, 1024);
  k_gn<0, true><<<256, 512, 0, stream>>>(pw, high, pw, he_gn2_g, he_gn2_b,
                                         alpha, 0.f, 12, 1024, 10);
  // 6) IWT + residual -> out
  k_iwt<<<4096, 256, 0, stream>>>(x, proj, pw, out);
  // 7) FFN
  k_conv1x1<128, 4><<<dim3(4, 16, 8), 256, 0, stream>>>(out, ffn_w1, f1, 256, 4096);
  k_gn<2, false><<<256, 512, 0, stream>>>(f1, nullptr, f1, ffn_gn1_g, ffn_gn1_b,
                                          nullptr, 0.f, 8, 4096, 12);
  k_conv1x1<256, 2><<<dim3(8, 8, 8), 256, 0, stream>>>(f1, ffn_w2, f3, 128, 4096);
  k_gn<0, true><<<256, 512, 0, stream>>>(f3, out, out, ffn_gn2_g, ffn_gn2_b,
                                         nullptr, 0.1f, 4, 4096, 12);
  (void)in_sizes; (void)n_in; (void)out_size; (void)ws_size;
}

// Round 6
// 518.217 us; speedup vs baseline: 1.7670x; 1.7670x over previous
//
#include <hip/hip_runtime.h>
#include <cstdint>
#include <cstddef>

// Dims (fixed by the problem)
#define BB 8
#define CC 128
#define C3 384
#define HH 64
#define H2 32
#define NPIX 1024   // 32*32
#define N4 4096     // 64*64
#define NHD 8
#define HD 16

typedef _Float16 h2f __attribute__((ext_vector_type(2)));

union HU { uint32_t u; h2f h; };
union U4H { uint4 u; h2f h[4]; };

__device__ inline h2f pkrtz(float a, float b) {
  // __builtin_amdgcn_cvt_pkrtz returns a __fp16 vector type; bit-cast to h2f.
  return __builtin_bit_cast(h2f, __builtin_amdgcn_cvt_pkrtz(a, b));
}

__device__ inline h2f shflh(h2f v, int m) {
  HU x; x.h = v;
  x.u = (uint32_t)__shfl_xor((int)x.u, m);
  return x.h;
}

// ---------------- K1: Haar DWT ----------------
__global__ __launch_bounds__(256) void k_dwt(const float* __restrict__ x,
                                             float* __restrict__ ll,
                                             float* __restrict__ high) {
  int idx = blockIdx.x * 256 + threadIdx.x;   // B*C*32*32 = 1,048,576
  int w = idx & 31, h = (idx >> 5) & 31, c = (idx >> 10) & 127, b = idx >> 17;
  const float* xp = x + ((size_t)(b * CC + c) * HH + 2 * h) * HH + 2 * w;
  float x1 = xp[0];
  float x2 = xp[HH];
  float x3 = xp[1];
  float x4 = xp[HH + 1];
  int n = h * H2 + w;
  ll[(size_t)(b * CC + c) * NPIX + n]              = 0.5f * ( x1 + x2 + x3 + x4);
  high[((size_t)b * C3 + c) * NPIX + n]            = 0.5f * (-x1 - x2 + x3 + x4);
  high[((size_t)b * C3 + CC + c) * NPIX + n]       = 0.5f * (-x1 + x2 - x3 + x4);
  high[((size_t)b * C3 + 2 * CC + c) * NPIX + n]   = 0.5f * ( x1 - x2 - x3 + x4);
}

// ---------------- conv1x1: pure-register GEMV per pixel ----------------
template <int CIN, int P>
__global__ __launch_bounds__(256) void k_conv1x1(const float* __restrict__ in,
                                                 const float* __restrict__ w,
                                                 float* __restrict__ out,
                                                 int Cout, int Npix) {
  int tid = threadIdx.x;
  int n0 = (blockIdx.x * 256 + tid) * P;
  int o0 = blockIdx.y * 16;
  int b = blockIdx.z;
  const float* inb = in + (size_t)b * CIN * Npix + n0;
  const float* wb = w + (size_t)o0 * CIN;
  float acc[16][P];
#pragma unroll
  for (int o = 0; o < 16; ++o)
#pragma unroll
    for (int p = 0; p < P; ++p) acc[o][p] = 0.f;

  for (int c0 = 0; c0 < CIN; c0 += 8) {
#pragma unroll
    for (int c = 0; c < 8; ++c) {
      float vv[P];
      const float* ip = inb + (size_t)(c0 + c) * Npix;
      if constexpr (P == 4) {
        float4 t = *(const float4*)ip;
        vv[0] = t.x; vv[1] = t.y; vv[2] = t.z; vv[3] = t.w;
      } else if constexpr (P == 2) {
        float2 t = *(const float2*)ip;
        vv[0] = t.x; vv[1] = t.y;
      } else {
        vv[0] = ip[0];
      }
#pragma unroll
      for (int o = 0; o < 16; ++o) {
        float wc = wb[(size_t)o * CIN + c0 + c];   // uniform -> s_load
#pragma unroll
        for (int p = 0; p < P; ++p) acc[o][p] = fmaf(wc, vv[p], acc[o][p]);
      }
    }
  }
  size_t ob = ((size_t)b * Cout + o0) * Npix + n0;
#pragma unroll
  for (int o = 0; o < 16; ++o) {
    float* op = out + ob + (size_t)o * Npix;
    if constexpr (P == 4) {
      *(float4*)op = make_float4(acc[o][0], acc[o][1], acc[o][2], acc[o][3]);
    } else if constexpr (P == 2) {
      *(float2*)op = make_float2(acc[o][0], acc[o][1]);
    } else {
      op[0] = acc[o][0];
    }
  }
}

// ---------------- K2b: split qkv + l2norm q,k; emit packed fp16 ----------------
// qkv (b, 3*128, n) -> qh/kh/vh rows of 16 halves (2 x uint4 per row),
// row index = (b*8+h)*1024 + n, d contiguous.
__global__ __launch_bounds__(256) void k_qkvnorm(const float* __restrict__ qkv,
                                                 uint4* __restrict__ qh,
                                                 uint4* __restrict__ kh,
                                                 uint4* __restrict__ vh) {
  int idx = blockIdx.x * 256 + threadIdx.x;  // 65536 = B*NH*NPIX
  int n = idx & 1023, h = (idx >> 10) & 7, b = idx >> 13;
  const float* base = qkv + ((size_t)b * C3 + h * HD) * NPIX + n;
  float q[HD], k[HD], vv[HD];
  float sq = 0.f, sk = 0.f;
#pragma unroll
  for (int d = 0; d < HD; ++d) {
    q[d] = base[(size_t)d * NPIX];
    k[d] = base[(size_t)(CC + d) * NPIX];
    vv[d] = base[(size_t)(2 * CC + d) * NPIX];
    sq += q[d] * q[d];
    sk += k[d] * k[d];
  }
  float rq = 1.f / fmaxf(sqrtf(sq), 1e-12f);
  float rk = 1.f / fmaxf(sqrtf(sk), 1e-12f);
#pragma unroll
  for (int g = 0; g < 2; ++g) {
    U4H pq, pk, pv;
#pragma unroll
    for (int d = 0; d < 4; ++d) {
      int e = g * 8 + 2 * d;
      pq.h[d] = pkrtz(q[e] * rq, q[e + 1] * rq);
      pk.h[d] = pkrtz(k[e] * rk, k[e + 1] * rk);
      pv.h[d] = pkrtz(vv[e], vv[e + 1]);
    }
    qh[(size_t)idx * 2 + g] = pq.u;
    kh[(size_t)idx * 2 + g] = pk.u;
    vh[(size_t)idx * 2 + g] = pv.u;
  }
}

// ---------------- K3: sparse top-k attention, fp16-packed ----------------
// 4 q-rows per wave; lane L covers keys {i*64 + L}. K/V loaded once per
// wave as packed halves (32B/row). QK^T via v_dot2_f32_f16 (fp32 accum).
// Scores/p held as half2 (32 regs). Bisection: f16 compare + ballot.
// AV accumulated with packed fp16 fma. Register budget ~120 -> no spill.
__global__ __launch_bounds__(256) void k_attn(const uint32_t* __restrict__ qh,
                                              const uint4* __restrict__ kh,
                                              const uint4* __restrict__ vh,
                                              float* __restrict__ attn_out) {
  __shared__ uint32_t q_lds[128];
  int tid = threadIdx.x;
  int lane = tid & 63;
  int wave = tid >> 6;
  int blk = blockIdx.x;            // 4096 blocks; 64 blocks per (b,h)
  int row0 = blk * 16;
  int bh = blk >> 6;
  // stage the block's 16 q-rows (16 x 8 u32 = 128 u32, coalesced)
  if (tid < 128) q_lds[tid] = qh[(size_t)blk * 128 + tid];
  __syncthreads();
  // this wave's 4 q rows -> VGPRs (broadcast LDS reads)
  h2f qs2[4][8];
  const uint32_t* qw = &q_lds[wave * 32];
#pragma unroll
  for (int q = 0; q < 4; ++q)
#pragma unroll
    for (int d = 0; d < 8; ++d) {
      HU u; u.u = qw[q * 8 + d];
      qs2[q][d] = u.h;
    }

  const uint4* kb = kh + (size_t)bh * 2048;   // 1024 rows * 2 uint4
  const uint4* vb = vh + (size_t)bh * 2048;

  // ---- phase 1: scores (fdot2, fp32 accum), packed into half2 ----
  h2f s2[4][8];
  float se[4];
#pragma unroll
  for (int i = 0; i < 16; ++i) {
    const uint4* kr = kb + (size_t)(i * 64 + lane) * 2;
    U4H u0, u1;
    u0.u = kr[0]; u1.u = kr[1];
    h2f k2[8];
#pragma unroll
    for (int d = 0; d < 4; ++d) { k2[d] = u0.h[d]; k2[4 + d] = u1.h[d]; }
#pragma unroll
    for (int q = 0; q < 4; ++q) {
      float acc = 0.f;
#pragma unroll
      for (int d = 0; d < 8; ++d)
        acc = __builtin_amdgcn_fdot2(qs2[q][d], k2[d], acc, false);
      acc *= 0.25f;                        // hd^-0.5; |acc| <= 0.25
      if (i & 1) s2[q][i >> 1] = pkrtz(se[q], acc);
      else       se[q] = acc;
    }
  }

  // ---- bisect for 512th-largest: f16 compare + ballot (SALU adds) ----
  float lo[4], hi[4];
  _Float16 hlo[4];
#pragma unroll
  for (int q = 0; q < 4; ++q) { lo[q] = -0.26f; hi[q] = 0.26f; hlo[q] = (_Float16)(-0.26f); }
  for (int it = 0; it < 14; ++it) {
#pragma unroll
    for (int q = 0; q < 4; ++q) {
      float mid = 0.5f * (lo[q] + hi[q]);
      _Float16 hm = (_Float16)mid;
      int c = 0;
#pragma unroll
      for (int j = 0; j < 8; ++j) {
        h2f t = s2[q][j];
        c += __popcll(__ballot(t[0] >= hm));
        c += __popcll(__ballot(t[1] >= hm));
      }
      if (c >= 512) { lo[q] = mid; hlo[q] = hm; } else hi[q] = mid;
    }
  }

  // ---- masked softmax in place (s2 -> unnormalized p, packed) ----
  float inv[4];
#pragma unroll
  for (int q = 0; q < 4; ++q) {
    float sum = 0.f;
#pragma unroll
    for (int j = 0; j < 8; ++j) {
      h2f t = s2[q][j];
      float p0 = (t[0] >= hlo[q]) ? __expf((float)t[0]) : 0.f;
      float p1 = (t[1] >= hlo[q]) ? __expf((float)t[1]) : 0.f;
      sum += p0 + p1;
      s2[q][j] = pkrtz(p0, p1);
    }
#pragma unroll
    for (int off = 32; off > 0; off >>= 1) sum += __shfl_xor(sum, off);
    inv[q] = 1.f / sum;
  }

  // ---- phase 2: AV (packed fp16 fma) ----
  h2f ov2[4][8];
#pragma unroll
  for (int q = 0; q < 4; ++q)
#pragma unroll
    for (int d = 0; d < 8; ++d) ov2[q][d] = (h2f)0;
#pragma unroll
  for (int i = 0; i < 16; ++i) {
    const uint4* vr = vb + (size_t)(i * 64 + lane) * 2;
    U4H u0, u1;
    u0.u = vr[0]; u1.u = vr[1];
    h2f v2[8];
#pragma unroll
    for (int d = 0; d < 4; ++d) { v2[d] = u0.h[d]; v2[4 + d] = u1.h[d]; }
#pragma unroll
    for (int q = 0; q < 4; ++q) {
      h2f t = s2[q][i >> 1];
      _Float16 pf = (i & 1) ? t[1] : t[0];
      h2f pp = (h2f){pf, pf};
#pragma unroll
      for (int d = 0; d < 8; ++d)
        ov2[q][d] = __builtin_elementwise_fma(pp, v2[d], ov2[q][d]);
    }
  }

  // ---- fold-transpose reduce (high/low split): lane L -> dim bitrev4(L) ----
  int b = bh >> 3, h = bh & 7;
  int dim = ((lane & 1) << 3) | ((lane & 2) << 1) | ((lane & 4) >> 1) | ((lane & 8) >> 3);
#pragma unroll
  for (int q = 0; q < 4; ++q) {
    bool m0 = (lane & 1) != 0;
    h2f B1[4];
#pragma unroll
    for (int p = 0; p < 4; ++p) {
      h2f r0 = shflh(ov2[q][p], 1);
      h2f r1 = shflh(ov2[q][p + 4], 1);
      h2f a0 = ov2[q][p] + r0;
      h2f a1 = ov2[q][p + 4] + r1;
      B1[p] = m0 ? a1 : a0;
    }
    bool m1 = (lane & 2) != 0;
    h2f B2[2];
#pragma unroll
    for (int p = 0; p < 2; ++p) {
      h2f r0 = shflh(B1[p], 2);
      h2f r1 = shflh(B1[p + 2], 2);
      h2f a0 = B1[p] + r0;
      h2f a1 = B1[p + 2] + r1;
      B2[p] = m1 ? a1 : a0;
    }
    bool m2 = (lane & 4) != 0;
    {
      h2f r0 = shflh(B2[0], 4);
      h2f r1 = shflh(B2[1], 4);
      h2f a0 = B2[0] + r0;
      h2f a1 = B2[1] + r1;
      B2[0] = m2 ? a1 : a0;
    }
    h2f r = shflh(B2[0], 8);
    h2f t = B2[0] + r;
    bool m3 = (lane & 8) != 0;
    float wf = m3 ? (float)t[1] : (float)t[0];
    wf += __shfl_xor(wf, 16);
    wf += __shfl_xor(wf, 32);
    if (lane < 16) {
      int n = (row0 + wave * 4 + q) & 1023;
      attn_out[((size_t)(b * CC + h * HD + dim) * NPIX) + n] = wf * inv[q];
    }
  }
}

// ---------------- K5a: depthwise 3x3 SAME conv ----------------
__global__ __launch_bounds__(256) void k_dwconv(const float* __restrict__ in,
                                                const float* __restrict__ w,
                                                float* __restrict__ out) {
  int n = blockIdx.x * 256 + threadIdx.x;
  int c = blockIdx.y, b = blockIdx.z;
  int i = n >> 5, j = n & 31;
  const float* inb = in + ((size_t)b * C3 + c) * NPIX;
  const float* wc = w + c * 9;
  float acc = 0.f;
#pragma unroll
  for (int di = -1; di <= 1; ++di) {
    int ii = i + di;
    if (ii < 0 || ii > 31) continue;
#pragma unroll
    for (int dj = -1; dj <= 1; ++dj) {
      int jj = j + dj;
      if (jj < 0 || jj > 31) continue;
      acc += inb[ii * 32 + jj] * wc[(di + 1) * 3 + (dj + 1)];
    }
  }
  out[((size_t)b * C3 + c) * NPIX + n] = acc;
}

// ---------------- GroupNorm (32 groups) + fused epilogue, float4, 512 thr ----
template <int ACT, bool HAS_RES>
__global__ __launch_bounds__(512) void k_gn(const float* __restrict__ x,
                                            const float* __restrict__ res,
                                            float* __restrict__ out,
                                            const float* __restrict__ gamma,
                                            const float* __restrict__ beta,
                                            const float* __restrict__ alpha_ptr,
                                            float alpha_const,
                                            int chPerGroup, int Npix, int nshift) {
  int g = blockIdx.x & 31, b = blockIdx.x >> 5;
  int Cout = 32 * chPerGroup;
  int elems = chPerGroup * Npix;
  int nv = elems >> 2;
  size_t base = ((size_t)b * Cout + g * chPerGroup) * Npix;
  const float4* xv = (const float4*)(x + base);
  int tid = threadIdx.x;
  float s = 0.f, s2 = 0.f;
  for (int i = tid; i < nv; i += 512) {
    float4 v = xv[i];
    s += v.x + v.y + v.z + v.w;
    s2 += v.x * v.x + v.y * v.y + v.z * v.z + v.w * v.w;
  }
  __shared__ float ls[512], ls2[512];
  ls[tid] = s; ls2[tid] = s2;
  __syncthreads();
  for (int st = 256; st > 0; st >>= 1) {
    if (tid < st) { ls[tid] += ls[tid + st]; ls2[tid] += ls2[tid + st]; }
    __syncthreads();
  }
  float inv_n = 1.f / (float)elems;
  float mean = ls[0] * inv_n;
  float var = ls2[0] * inv_n - mean * mean;
  float rstd = rsqrtf(var + 1e-6f);
  float a = alpha_ptr ? alpha_ptr[0] : alpha_const;
  const float4* rv = (const float4*)(res + base);
  float4* ov = (float4*)(out + base);
  int cshift = nshift - 2;
  for (int i = tid; i < nv; i += 512) {
    float4 v = xv[i];
    int cc = g * chPerGroup + (i >> cshift);
    float gm = gamma[cc], bt = beta[cc];
    float r[4] = {v.x, v.y, v.z, v.w};
#pragma unroll
    for (int p = 0; p < 4; ++p) {
      float gnv = (r[p] - mean) * rstd * gm + bt;
      if (ACT == 1)      r[p] = gnv / (1.f + __expf(-gnv));
      else if (ACT == 2) r[p] = 0.5f * gnv * (1.f + erff(gnv * 0.70710678118654752f));
      else               r[p] = gnv;
    }
    float4 o;
    if (HAS_RES) {
      float4 rr = rv[i];
      o = make_float4(rr.x + a * r[0], rr.y + a * r[1], rr.z + a * r[2], rr.w + a * r[3]);
    } else {
      o = make_float4(r[0], r[1], r[2], r[3]);
    }
    ov[i] = o;
  }
}

// ---------------- K6: IWT + residual ----------------
__global__ __launch_bounds__(256) void k_iwt(const float* __restrict__ x,
                                             const float* __restrict__ s1,
                                             const float* __restrict__ hout,
                                             float* __restrict__ out) {
  int idx = blockIdx.x * 256 + threadIdx.x;  // B*C*32*32
  int w = idx & 31, h = (idx >> 5) & 31, c = (idx >> 10) & 127, b = idx >> 17;
  int n = h * 32 + w;
  float ll = s1[(size_t)(b * CC + c) * NPIX + n];
  float lh = hout[((size_t)b * C3 + c) * NPIX + n];
  float hl = hout[((size_t)b * C3 + CC + c) * NPIX + n];
  float hh = hout[((size_t)b * C3 + 2 * CC + c) * NPIX + n];
  float va = ll - lh - hl + hh;
  float vb = ll - lh + hl - hh;
  float vc = ll + lh - hl - hh;
  float vd = ll + lh + hl + hh;
  size_t xb = ((size_t)(b * CC + c) * HH + 2 * h) * HH + 2 * w;
  out[xb]          = x[xb]          + 0.1f * va;
  out[xb + 1]      = x[xb + 1]      + 0.1f * vc;
  out[xb + HH]     = x[xb + HH]     + 0.1f * vb;
  out[xb + HH + 1] = x[xb + HH + 1] + 0.1f * vd;
}

extern "C" void kernel_launch(void* const* d_in, const int* in_sizes, int n_in,
                              void* d_out, int out_size, void* d_ws, size_t ws_size,
                              hipStream_t stream) {
  const float* x         = (const float*)d_in[0];
  const float* qkv_w     = (const float*)d_in[1];
  const float* proj_w    = (const float*)d_in[2];
  const float* attn_gn_g = (const float*)d_in[3];
  const float* attn_gn_b = (const float*)d_in[4];
  const float* he_dw_w   = (const float*)d_in[5];
  const float* he_gn1_g  = (const float*)d_in[6];
  const float* he_gn1_b  = (const float*)d_in[7];
  const float* he_pw_w   = (const float*)d_in[8];
  const float* he_gn2_g  = (const float*)d_in[9];
  const float* he_gn2_b  = (const float*)d_in[10];
  const float* alpha     = (const float*)d_in[11];
  const float* ffn_w1    = (const float*)d_in[12];
  const float* ffn_gn1_g = (const float*)d_in[13];
  const float* ffn_gn1_b = (const float*)d_in[14];
  const float* ffn_w2    = (const float*)d_in[15];
  const float* ffn_gn2_g = (const float*)d_in[16];
  const float* ffn_gn2_b = (const float*)d_in[17];
  float* out = (float*)d_out;

  float* ws = (float*)d_ws;
  float* ll   = ws;              // 1,048,576
  float* high = ws + 1048576;    // 3,145,728
  float* qkv  = ws + 4194304;    // 3,145,728 ; reused as y1
  float* qnkv = ws + 7340032;    // 3,145,728 ; qh|kh|vh (fp16) ; reused as pw/h_out
  float* atto = ws + 10485760;   // 1,048,576
  float* proj = ws + 11534336;   // 1,048,576
  float* f1   = ws + 12582912;   // 8,388,608
  float* f3   = ws + 20971520;   // 4,194,304
  // packed fp16 q/k/v: 65536 rows x 32B = 2 MB each (within qnkv's 12 MB)
  uint4* qh = (uint4*)qnkv;
  uint4* kh = (uint4*)(qnkv + 524288);
  uint4* vh = (uint4*)(qnkv + 1048576);
  float* y1 = qkv;
  float* pw = qnkv;

  // 1) DWT
  k_dwt<<<4096, 256, 0, stream>>>(x, ll, high);
  // 2) qkv = conv1x1(ll, qkv_w); split + l2norm -> packed fp16
  k_conv1x1<128, 2><<<dim3(2, 24, 8), 256, 0, stream>>>(ll, qkv_w, qkv, 384, 1024);
  k_qkvnorm<<<256, 256, 0, stream>>>(qkv, qh, kh, vh);
  // 3) sparse attention (4 q-rows per wave, fp16-packed state)
  k_attn<<<4096, 256, 0, stream>>>((const uint32_t*)qh, kh, vh, atto);
  // 4) proj + groupnorm, s1 = ll + gn(proj)
  k_conv1x1<128, 1><<<dim3(4, 8, 8), 256, 0, stream>>>(atto, proj_w, proj, 128, 1024);
  k_gn<0, true><<<256, 512, 0, stream>>>(proj, ll, proj, attn_gn_g, attn_gn_b,
                                         nullptr, 1.0f, 4, 1024, 10);
  // 5) high enhance
  k_dwconv<<<dim3(4, 384, 8), 256, 0, stream>>>(high, he_dw_w, y1);
  k_gn<1, false><<<256, 512, 0, stream>>>(y1, nullptr, y1, he_gn1_g, he_gn1_b,
                                          nullptr, 0.f, 12, 1024, 10);
  k_conv1x1<384, 2><<<dim3(2, 24, 8), 256, 0, stream>>>(y1, he_pw_w, pw, 384, 1024);
  k_gn<0, true><<<256, 512, 0, stream>>>(pw, high, pw, he_gn2_g, he_gn2_b,
                                         alpha, 0.f, 12, 1024, 10);
  // 6) IWT + residual -> out
  k_iwt<<<4096, 256, 0, stream>>>(x, proj, pw, out);
  // 7) FFN
  k_conv1x1<128, 4><<<dim3(4, 16, 8), 256, 0, stream>>>(out, ffn_w1, f1, 256, 4096);
  k_gn<2, false><<<256, 512, 0, stream>>>(f1, nullptr, f1, ffn_gn1_g, ffn_gn1_b,
                                          nullptr, 0.f, 8, 4096, 12);
  k_conv1x1<256, 2><<<dim3(8, 8, 8), 256, 0, stream>>>(f1, ffn_w2, f3, 128, 4096);
  k_gn<0, true><<<256, 512, 0, stream>>>(f3, out, out, ffn_gn2_g, ffn_gn2_b,
                                         nullptr, 0.1f, 4, 4096, 12);
  (void)in_sizes; (void)n_in; (void)out_size; (void)ws_size;
}

// Round 7
// 476.270 us; speedup vs baseline: 1.9226x; 1.0881x over previous
//
#include <hip/hip_runtime.h>
#include <cstdint>
#include <cstddef>

// Dims (fixed by the problem)
#define BB 8
#define CC 128
#define C3 384
#define HH 64
#define H2 32
#define NPIX 1024   // 32*32
#define N4 4096     // 64*64
#define NHD 8
#define HD 16

typedef _Float16 h2f __attribute__((ext_vector_type(2)));

union HU { uint32_t u; h2f h; };
union U4H { uint4 u; h2f h[4]; };

__device__ inline h2f pkrtz(float a, float b) {
  return __builtin_bit_cast(h2f, __builtin_amdgcn_cvt_pkrtz(a, b));
}

__device__ inline h2f shflh(h2f v, int m) {
  HU x; x.h = v;
  x.u = (uint32_t)__shfl_xor((int)x.u, m);
  return x.h;
}

// ---------------- K1: Haar DWT ----------------
__global__ __launch_bounds__(256) void k_dwt(const float* __restrict__ x,
                                             float* __restrict__ ll,
                                             float* __restrict__ high) {
  int idx = blockIdx.x * 256 + threadIdx.x;   // B*C*32*32 = 1,048,576
  int w = idx & 31, h = (idx >> 5) & 31, c = (idx >> 10) & 127, b = idx >> 17;
  const float* xp = x + ((size_t)(b * CC + c) * HH + 2 * h) * HH + 2 * w;
  float x1 = xp[0];
  float x2 = xp[HH];
  float x3 = xp[1];
  float x4 = xp[HH + 1];
  int n = h * H2 + w;
  ll[(size_t)(b * CC + c) * NPIX + n]              = 0.5f * ( x1 + x2 + x3 + x4);
  high[((size_t)b * C3 + c) * NPIX + n]            = 0.5f * (-x1 - x2 + x3 + x4);
  high[((size_t)b * C3 + CC + c) * NPIX + n]       = 0.5f * (-x1 + x2 - x3 + x4);
  high[((size_t)b * C3 + 2 * CC + c) * NPIX + n]   = 0.5f * ( x1 - x2 - x3 + x4);
}

// ---------------- conv1x1: register GEMV; OPT outs x P pixels per thread ----
// grid = (Npix/(256*P), Cout/OPT, B). OPT small (4-8) keeps VGPR low and
// grids large (>=1024 blocks) so latency is hidden by occupancy.
template <int CIN, int P, int OPT>
__global__ __launch_bounds__(256) void k_conv1x1(const float* __restrict__ in,
                                                 const float* __restrict__ w,
                                                 float* __restrict__ out,
                                                 int Cout, int Npix) {
  int tid = threadIdx.x;
  int n0 = (blockIdx.x * 256 + tid) * P;
  int o0 = blockIdx.y * OPT;
  int b = blockIdx.z;
  const float* inb = in + (size_t)b * CIN * Npix + n0;
  const float* wb = w + (size_t)o0 * CIN;
  float acc[OPT][P];
#pragma unroll
  for (int o = 0; o < OPT; ++o)
#pragma unroll
    for (int p = 0; p < P; ++p) acc[o][p] = 0.f;

  for (int c0 = 0; c0 < CIN; c0 += 8) {
#pragma unroll
    for (int c = 0; c < 8; ++c) {
      float vv[P];
      const float* ip = inb + (size_t)(c0 + c) * Npix;
      if constexpr (P == 4) {
        float4 t = *(const float4*)ip;
        vv[0] = t.x; vv[1] = t.y; vv[2] = t.z; vv[3] = t.w;
      } else if constexpr (P == 2) {
        float2 t = *(const float2*)ip;
        vv[0] = t.x; vv[1] = t.y;
      } else {
        vv[0] = ip[0];
      }
#pragma unroll
      for (int o = 0; o < OPT; ++o) {
        float wc = wb[(size_t)o * CIN + c0 + c];   // uniform -> s_load
#pragma unroll
        for (int p = 0; p < P; ++p) acc[o][p] = fmaf(wc, vv[p], acc[o][p]);
      }
    }
  }
  size_t ob = ((size_t)b * Cout + o0) * Npix + n0;
#pragma unroll
  for (int o = 0; o < OPT; ++o) {
    float* op = out + ob + (size_t)o * Npix;
    if constexpr (P == 4) {
      *(float4*)op = make_float4(acc[o][0], acc[o][1], acc[o][2], acc[o][3]);
    } else if constexpr (P == 2) {
      *(float2*)op = make_float2(acc[o][0], acc[o][1]);
    } else {
      op[0] = acc[o][0];
    }
  }
}

// ---------------- K2b: split qkv + l2norm q,k; emit packed fp16 ----------------
__global__ __launch_bounds__(256) void k_qkvnorm(const float* __restrict__ qkv,
                                                 uint4* __restrict__ qh,
                                                 uint4* __restrict__ kh,
                                                 uint4* __restrict__ vh) {
  int idx = blockIdx.x * 256 + threadIdx.x;  // 65536 = B*NH*NPIX
  int n = idx & 1023, h = (idx >> 10) & 7, b = idx >> 13;
  const float* base = qkv + ((size_t)b * C3 + h * HD) * NPIX + n;
  float q[HD], k[HD], vv[HD];
  float sq = 0.f, sk = 0.f;
#pragma unroll
  for (int d = 0; d < HD; ++d) {
    q[d] = base[(size_t)d * NPIX];
    k[d] = base[(size_t)(CC + d) * NPIX];
    vv[d] = base[(size_t)(2 * CC + d) * NPIX];
    sq += q[d] * q[d];
    sk += k[d] * k[d];
  }
  float rq = 1.f / fmaxf(sqrtf(sq), 1e-12f);
  float rk = 1.f / fmaxf(sqrtf(sk), 1e-12f);
#pragma unroll
  for (int g = 0; g < 2; ++g) {
    U4H pq, pk, pv;
#pragma unroll
    for (int d = 0; d < 4; ++d) {
      int e = g * 8 + 2 * d;
      pq.h[d] = pkrtz(q[e] * rq, q[e + 1] * rq);
      pk.h[d] = pkrtz(k[e] * rk, k[e + 1] * rk);
      pv.h[d] = pkrtz(vv[e], vv[e + 1]);
    }
    qh[(size_t)idx * 2 + g] = pq.u;
    kh[(size_t)idx * 2 + g] = pk.u;
    vh[(size_t)idx * 2 + g] = pv.u;
  }
}

// ---------------- K3: sparse top-k attention, fp16-packed ----------------
__global__ __launch_bounds__(256) void k_attn(const uint32_t* __restrict__ qh,
                                              const uint4* __restrict__ kh,
                                              const uint4* __restrict__ vh,
                                              float* __restrict__ attn_out) {
  __shared__ uint32_t q_lds[128];
  int tid = threadIdx.x;
  int lane = tid & 63;
  int wave = tid >> 6;
  int blk = blockIdx.x;            // 4096 blocks; 64 blocks per (b,h)
  int row0 = blk * 16;
  int bh = blk >> 6;
  if (tid < 128) q_lds[tid] = qh[(size_t)blk * 128 + tid];
  __syncthreads();
  h2f qs2[4][8];
  const uint32_t* qw = &q_lds[wave * 32];
#pragma unroll
  for (int q = 0; q < 4; ++q)
#pragma unroll
    for (int d = 0; d < 8; ++d) {
      HU u; u.u = qw[q * 8 + d];
      qs2[q][d] = u.h;
    }

  const uint4* kb = kh + (size_t)bh * 2048;   // 1024 rows * 2 uint4
  const uint4* vb = vh + (size_t)bh * 2048;

  // ---- phase 1: scores (fdot2, fp32 accum), packed into half2 ----
  h2f s2[4][8];
  float se[4];
#pragma unroll
  for (int i = 0; i < 16; ++i) {
    const uint4* kr = kb + (size_t)(i * 64 + lane) * 2;
    U4H u0, u1;
    u0.u = kr[0]; u1.u = kr[1];
    h2f k2[8];
#pragma unroll
    for (int d = 0; d < 4; ++d) { k2[d] = u0.h[d]; k2[4 + d] = u1.h[d]; }
#pragma unroll
    for (int q = 0; q < 4; ++q) {
      float acc = 0.f;
#pragma unroll
      for (int d = 0; d < 8; ++d)
        acc = __builtin_amdgcn_fdot2(qs2[q][d], k2[d], acc, false);
      acc *= 0.25f;                        // hd^-0.5; |acc| <= 0.25
      if (i & 1) s2[q][i >> 1] = pkrtz(se[q], acc);
      else       se[q] = acc;
    }
  }

  // ---- bisect for 512th-largest: f16 compare + ballot (SALU adds) ----
  // 12 iters: resolution 0.52/2^12 = 1.3e-4 ~ fp16 ulp at 0.25 (more is noise)
  float lo[4], hi[4];
  _Float16 hlo[4];
#pragma unroll
  for (int q = 0; q < 4; ++q) { lo[q] = -0.26f; hi[q] = 0.26f; hlo[q] = (_Float16)(-0.26f); }
  for (int it = 0; it < 12; ++it) {
#pragma unroll
    for (int q = 0; q < 4; ++q) {
      float mid = 0.5f * (lo[q] + hi[q]);
      _Float16 hm = (_Float16)mid;
      int c = 0;
#pragma unroll
      for (int j = 0; j < 8; ++j) {
        h2f t = s2[q][j];
        c += __popcll(__ballot(t[0] >= hm));
        c += __popcll(__ballot(t[1] >= hm));
      }
      if (c >= 512) { lo[q] = mid; hlo[q] = hm; } else hi[q] = mid;
    }
  }

  // ---- masked softmax in place (s2 -> unnormalized p, packed) ----
  float inv[4];
#pragma unroll
  for (int q = 0; q < 4; ++q) {
    float sum = 0.f;
#pragma unroll
    for (int j = 0; j < 8; ++j) {
      h2f t = s2[q][j];
      float p0 = (t[0] >= hlo[q]) ? __expf((float)t[0]) : 0.f;
      float p1 = (t[1] >= hlo[q]) ? __expf((float)t[1]) : 0.f;
      sum += p0 + p1;
      s2[q][j] = pkrtz(p0, p1);
    }
#pragma unroll
    for (int off = 32; off > 0; off >>= 1) sum += __shfl_xor(sum, off);
    inv[q] = 1.f / sum;
  }

  // ---- phase 2: AV (packed fp16 fma) ----
  h2f ov2[4][8];
#pragma unroll
  for (int q = 0; q < 4; ++q)
#pragma unroll
    for (int d = 0; d < 8; ++d) ov2[q][d] = (h2f)0;
#pragma unroll
  for (int i = 0; i < 16; ++i) {
    const uint4* vr = vb + (size_t)(i * 64 + lane) * 2;
    U4H u0, u1;
    u0.u = vr[0]; u1.u = vr[1];
    h2f v2[8];
#pragma unroll
    for (int d = 0; d < 4; ++d) { v2[d] = u0.h[d]; v2[4 + d] = u1.h[d]; }
#pragma unroll
    for (int q = 0; q < 4; ++q) {
      h2f t = s2[q][i >> 1];
      _Float16 pf = (i & 1) ? t[1] : t[0];
      h2f pp = (h2f){pf, pf};
#pragma unroll
      for (int d = 0; d < 8; ++d)
        ov2[q][d] = __builtin_elementwise_fma(pp, v2[d], ov2[q][d]);
    }
  }

  // ---- fold-transpose reduce (high/low split): lane L -> dim bitrev4(L) ----
  int b = bh >> 3, h = bh & 7;
  int dim = ((lane & 1) << 3) | ((lane & 2) << 1) | ((lane & 4) >> 1) | ((lane & 8) >> 3);
#pragma unroll
  for (int q = 0; q < 4; ++q) {
    bool m0 = (lane & 1) != 0;
    h2f B1[4];
#pragma unroll
    for (int p = 0; p < 4; ++p) {
      h2f r0 = shflh(ov2[q][p], 1);
      h2f r1 = shflh(ov2[q][p + 4], 1);
      h2f a0 = ov2[q][p] + r0;
      h2f a1 = ov2[q][p + 4] + r1;
      B1[p] = m0 ? a1 : a0;
    }
    bool m1 = (lane & 2) != 0;
    h2f B2[2];
#pragma unroll
    for (int p = 0; p < 2; ++p) {
      h2f r0 = shflh(B1[p], 2);
      h2f r1 = shflh(B1[p + 2], 2);
      h2f a0 = B1[p] + r0;
      h2f a1 = B1[p + 2] + r1;
      B2[p] = m1 ? a1 : a0;
    }
    bool m2 = (lane & 4) != 0;
    {
      h2f r0 = shflh(B2[0], 4);
      h2f r1 = shflh(B2[1], 4);
      h2f a0 = B2[0] + r0;
      h2f a1 = B2[1] + r1;
      B2[0] = m2 ? a1 : a0;
    }
    h2f r = shflh(B2[0], 8);
    h2f t = B2[0] + r;
    bool m3 = (lane & 8) != 0;
    float wf = m3 ? (float)t[1] : (float)t[0];
    wf += __shfl_xor(wf, 16);
    wf += __shfl_xor(wf, 32);
    if (lane < 16) {
      int n = (row0 + wave * 4 + q) & 1023;
      attn_out[((size_t)(b * CC + h * HD + dim) * NPIX) + n] = wf * inv[q];
    }
  }
}

// ---------------- K5a: depthwise 3x3 SAME conv ----------------
__global__ __launch_bounds__(256) void k_dwconv(const float* __restrict__ in,
                                                const float* __restrict__ w,
                                                float* __restrict__ out) {
  int n = blockIdx.x * 256 + threadIdx.x;
  int c = blockIdx.y, b = blockIdx.z;
  int i = n >> 5, j = n & 31;
  const float* inb = in + ((size_t)b * C3 + c) * NPIX;
  const float* wc = w + c * 9;
  float acc = 0.f;
#pragma unroll
  for (int di = -1; di <= 1; ++di) {
    int ii = i + di;
    if (ii < 0 || ii > 31) continue;
#pragma unroll
    for (int dj = -1; dj <= 1; ++dj) {
      int jj = j + dj;
      if (jj < 0 || jj > 31) continue;
      acc += inb[ii * 32 + jj] * wc[(di + 1) * 3 + (dj + 1)];
    }
  }
  out[((size_t)b * C3 + c) * NPIX + n] = acc;
}

// ---------------- GroupNorm (32 groups) + fused epilogue, float4, 512 thr ----
// Reduce: wave shfl-reduce -> 8-entry LDS -> broadcast (2 barriers).
template <int ACT, bool HAS_RES>
__global__ __launch_bounds__(512) void k_gn(const float* __restrict__ x,
                                            const float* __restrict__ res,
                                            float* __restrict__ out,
                                            const float* __restrict__ gamma,
                                            const float* __restrict__ beta,
                                            const float* __restrict__ alpha_ptr,
                                            float alpha_const,
                                            int chPerGroup, int Npix, int nshift) {
  int g = blockIdx.x & 31, b = blockIdx.x >> 5;
  int Cout = 32 * chPerGroup;
  int elems = chPerGroup * Npix;
  int nv = elems >> 2;
  size_t base = ((size_t)b * Cout + g * chPerGroup) * Npix;
  const float4* xv = (const float4*)(x + base);
  int tid = threadIdx.x;
  float s = 0.f, s2 = 0.f;
  for (int i = tid; i < nv; i += 512) {
    float4 v = xv[i];
    s += v.x + v.y + v.z + v.w;
    s2 += v.x * v.x + v.y * v.y + v.z * v.z + v.w * v.w;
  }
#pragma unroll
  for (int off = 32; off > 0; off >>= 1) {
    s += __shfl_xor(s, off);
    s2 += __shfl_xor(s2, off);
  }
  __shared__ float ls[8], ls2[8];
  int wv = tid >> 6, ln = tid & 63;
  if (ln == 0) { ls[wv] = s; ls2[wv] = s2; }
  __syncthreads();
  float st = 0.f, s2t = 0.f;
#pragma unroll
  for (int i = 0; i < 8; ++i) { st += ls[i]; s2t += ls2[i]; }
  float inv_n = 1.f / (float)elems;
  float mean = st * inv_n;
  float var = s2t * inv_n - mean * mean;
  float rstd = rsqrtf(var + 1e-6f);
  float a = alpha_ptr ? alpha_ptr[0] : alpha_const;
  const float4* rv = (const float4*)(res + base);
  float4* ov = (float4*)(out + base);
  int cshift = nshift - 2;
  for (int i = tid; i < nv; i += 512) {
    float4 v = xv[i];
    int cc = g * chPerGroup + (i >> cshift);
    float gm = gamma[cc], bt = beta[cc];
    float r[4] = {v.x, v.y, v.z, v.w};
#pragma unroll
    for (int p = 0; p < 4; ++p) {
      float gnv = (r[p] - mean) * rstd * gm + bt;
      if (ACT == 1)      r[p] = gnv / (1.f + __expf(-gnv));
      else if (ACT == 2) r[p] = 0.5f * gnv * (1.f + erff(gnv * 0.70710678118654752f));
      else               r[p] = gnv;
    }
    float4 o;
    if (HAS_RES) {
      float4 rr = rv[i];
      o = make_float4(rr.x + a * r[0], rr.y + a * r[1], rr.z + a * r[2], rr.w + a * r[3]);
    } else {
      o = make_float4(r[0], r[1], r[2], r[3]);
    }
    ov[i] = o;
  }
}

// ---------------- K6: IWT + residual ----------------
__global__ __launch_bounds__(256) void k_iwt(const float* __restrict__ x,
                                             const float* __restrict__ s1,
                                             const float* __restrict__ hout,
                                             float* __restrict__ out) {
  int idx = blockIdx.x * 256 + threadIdx.x;  // B*C*32*32
  int w = idx & 31, h = (idx >> 5) & 31, c = (idx >> 10) & 127, b = idx >> 17;
  int n = h * 32 + w;
  float ll = s1[(size_t)(b * CC + c) * NPIX + n];
  float lh = hout[((size_t)b * C3 + c) * NPIX + n];
  float hl = hout[((size_t)b * C3 + CC + c) * NPIX + n];
  float hh = hout[((size_t)b * C3 + 2 * CC + c) * NPIX + n];
  float va = ll - lh - hl + hh;
  float vb = ll - lh + hl - hh;
  float vc = ll + lh - hl - hh;
  float vd = ll + lh + hl + hh;
  size_t xb = ((size_t)(b * CC + c) * HH + 2 * h) * HH + 2 * w;
  out[xb]          = x[xb]          + 0.1f * va;
  out[xb + 1]      = x[xb + 1]      + 0.1f * vc;
  out[xb + HH]     = x[xb + HH]     + 0.1f * vb;
  out[xb + HH + 1] = x[xb + HH + 1] + 0.1f * vd;
}

extern "C" void kernel_launch(void* const* d_in, const int* in_sizes, int n_in,
                              void* d_out, int out_size, void* d_ws, size_t ws_size,
                              hipStream_t stream) {
  const float* x         = (const float*)d_in[0];
  const float* qkv_w     = (const float*)d_in[1];
  const float* proj_w    = (const float*)d_in[2];
  const float* attn_gn_g = (const float*)d_in[3];
  const float* attn_gn_b = (const float*)d_in[4];
  const float* he_dw_w   = (const float*)d_in[5];
  const float* he_gn1_g  = (const float*)d_in[6];
  const float* he_gn1_b  = (const float*)d_in[7];
  const float* he_pw_w   = (const float*)d_in[8];
  const float* he_gn2_g  = (const float*)d_in[9];
  const float* he_gn2_b  = (const float*)d_in[10];
  const float* alpha     = (const float*)d_in[11];
  const float* ffn_w1    = (const float*)d_in[12];
  const float* ffn_gn1_g = (const float*)d_in[13];
  const float* ffn_gn1_b = (const float*)d_in[14];
  const float* ffn_w2    = (const float*)d_in[15];
  const float* ffn_gn2_g = (const float*)d_in[16];
  const float* ffn_gn2_b = (const float*)d_in[17];
  float* out = (float*)d_out;

  float* ws = (float*)d_ws;
  float* ll   = ws;              // 1,048,576
  float* high = ws + 1048576;    // 3,145,728
  float* qkv  = ws + 4194304;    // 3,145,728 ; reused as y1
  float* qnkv = ws + 7340032;    // 3,145,728 ; qh|kh|vh (fp16) ; reused as pw/h_out
  float* atto = ws + 10485760;   // 1,048,576
  float* proj = ws + 11534336;   // 1,048,576
  float* f1   = ws + 12582912;   // 8,388,608
  float* f3   = ws + 20971520;   // 4,194,304
  uint4* qh = (uint4*)qnkv;
  uint4* kh = (uint4*)(qnkv + 524288);
  uint4* vh = (uint4*)(qnkv + 1048576);
  float* y1 = qkv;
  float* pw = qnkv;

  // 1) DWT
  k_dwt<<<4096, 256, 0, stream>>>(x, ll, high);
  // 2) qkv = conv1x1(ll, qkv_w); split + l2norm -> packed fp16
  k_conv1x1<128, 1, 8><<<dim3(4, 48, 8), 256, 0, stream>>>(ll, qkv_w, qkv, 384, 1024);
  k_qkvnorm<<<256, 256, 0, stream>>>(qkv, qh, kh, vh);
  // 3) sparse attention (4 q-rows per wave, fp16-packed state)
  k_attn<<<4096, 256, 0, stream>>>((const uint32_t*)qh, kh, vh, atto);
  // 4) proj + groupnorm, s1 = ll + gn(proj)
  k_conv1x1<128, 1, 4><<<dim3(4, 32, 8), 256, 0, stream>>>(atto, proj_w, proj, 128, 1024);
  k_gn<0, true><<<256, 512, 0, stream>>>(proj, ll, proj, attn_gn_g, attn_gn_b,
                                         nullptr, 1.0f, 4, 1024, 10);
  // 5) high enhance
  k_dwconv<<<dim3(4, 384, 8), 256, 0, stream>>>(high, he_dw_w, y1);
  k_gn<1, false><<<256, 512, 0, stream>>>(y1, nullptr, y1, he_gn1_g, he_gn1_b,
                                          nullptr, 0.f, 12, 1024, 10);
  k_conv1x1<384, 1, 8><<<dim3(4, 48, 8), 256, 0, stream>>>(y1, he_pw_w, pw, 384, 1024);
  k_gn<0, true><<<256, 512, 0, stream>>>(pw, high, pw, he_gn2_g, he_gn2_b,
                                         alpha, 0.f, 12, 1024, 10);
  // 6) IWT + residual -> out
  k_iwt<<<4096, 256, 0, stream>>>(x, proj, pw, out);
  // 7) FFN
  k_conv1x1<128, 2, 8><<<dim3(8, 32, 8), 256, 0, stream>>>(out, ffn_w1, f1, 256, 4096);
  k_gn<2, false><<<256, 512, 0, stream>>>(f1, nullptr, f1, ffn_gn1_g, ffn_gn1_b,
                                          nullptr, 0.f, 8, 4096, 12);
  k_conv1x1<256, 2, 8><<<dim3(8, 16, 8), 256, 0, stream>>>(f1, ffn_w2, f3, 128, 4096);
  k_gn<0, true><<<256, 512, 0, stream>>>(f3, out, out, ffn_gn2_g, ffn_gn2_b,
                                         nullptr, 0.1f, 4, 4096, 12);
  (void)in_sizes; (void)n_in; (void)out_size; (void)ws_size;
}